// Round 9
// baseline (166.206 us; speedup 1.0000x reference)
//
#include <hip/hip_runtime.h>
#include <hip/hip_bf16.h>

#define NE 8192
#define BATCH 64
#define NNZT (NE * 32)
#define KSPLIT 8
#define KCH (NE / KSPLIT)  // 1024 k per block
#define BK 64              // k per step
#define NSTEP (KCH / BK)   // 16 steps
#define TN 256             // W rows per block

typedef float f32x4 __attribute__((ext_vector_type(4)));
typedef unsigned u32x4 __attribute__((ext_vector_type(4)));
typedef unsigned u32x2 __attribute__((ext_vector_type(2)));
typedef short s16x8 __attribute__((ext_vector_type(8)));

__device__ __forceinline__ unsigned f2bf(float f) {
  unsigned u = __builtin_bit_cast(unsigned, f);
  return (u + 0x7FFFu + ((u >> 16) & 1u)) >> 16;  // RNE
}

// x fp32 [64][8192] -> bf16 (as ushort)
__global__ void k_convert_x(const float* __restrict__ x, unsigned short* __restrict__ xb) {
  int i = (blockIdx.x * 256 + threadIdx.x) * 4;
  float4 v = *reinterpret_cast<const float4*>(x + i);
  *reinterpret_cast<ushort4*>(xb + i) =
      make_ushort4((unsigned short)f2bf(v.x), (unsigned short)f2bf(v.y),
                   (unsigned short)f2bf(v.z), (unsigned short)f2bf(v.w));
}

__global__ void k_zero(float* __restrict__ p) {
  int i = (blockIdx.x * 256 + threadIdx.x) * 4;
  *reinterpret_cast<float4*>(p + i) = make_float4(0.f, 0.f, 0.f, 0.f);
}

// h = x @ W^T stored transposed ht[i][b], partial-K via atomicAdd.
// Read-byte-minimized: TN=256 rows/block cuts x re-read to 32 MB total
// (R7: 128 MB). 1 block/CU (grid 256), 8 waves, BK=64, LDS 80 KB dbuf.
// Loads stay coalesced (16 B/lane contiguous >=128 B segments); reg-staged
// global->reg->(bf16)->LDS with XOR swizzle ((row&7)<<4) on write AND read;
// barriers wait lgkmcnt only (reads never drained); 2-step reg ping-pong.
__global__ __launch_bounds__(512, 2) void k_dense(const unsigned short* __restrict__ xb,
                                                  const float* __restrict__ W,
                                                  float* __restrict__ ht) {
  __shared__ __align__(16) char smem[81920];  // [2][256][128B] W + [2][64][128B] x
  const int tid = threadIdx.x;
  const int wv = tid >> 6, l = tid & 63;
  const int kq = blockIdx.x & (KSPLIT - 1);
  const int i0 = (blockIdx.x >> 3) * TN;
  const int k0 = kq * KCH;

  // staging: wave wv stages W rows wv*32..+32 (8 dwordx4: 4 rows each) and
  // x rows wv*8..+8 (1 dwordx4: 8 rows x 16 B).
  const float* wsrc = W + (size_t)(i0 + wv * 32 + (l >> 4)) * NE + k0 + (l & 15) * 4;
  const unsigned short* xsrc = xb + (size_t)(wv * 8 + (l >> 3)) * NE + k0 + (l & 7) * 8;

  // fragment geometry (verified convention: A=x rows, B=W rows on lane&15)
  const int r16 = l & 15, q = l >> 4;
  const int fxor = (r16 & 7) << 4;
  const int wrow0 = wv * 32 + r16;  // + f*16
  // ds_write offsets
  const int wdr = wv * 32 + (l >> 4);        // + j*4 rows
  const int xdr = wv * 8 + (l >> 3);

  f32x4 acc0[4] = {}, acc1[4] = {};  // acc{f}[g]
  f32x4 wA[8], wB[8];
  u32x4 xA, xB;

#define LOADW(WR, XR, s)                                                           \
  do {                                                                             \
    _Pragma("unroll") for (int j = 0; j < 8; ++j)                                  \
        WR[j] = *reinterpret_cast<const f32x4*>(wsrc + (size_t)j * 4 * NE + (s)*BK); \
    XR = *reinterpret_cast<const u32x4*>(xsrc + (s)*BK);                           \
    __builtin_amdgcn_sched_barrier(0);                                             \
  } while (0)

#define STORE(WR, XR, buf)                                                         \
  do {                                                                             \
    _Pragma("unroll") for (int j = 0; j < 8; ++j) {                                \
      const int r_ = wdr + j * 4;                                                  \
      const int co_ = ((l & 15) * 8) ^ ((r_ & 7) << 4);                            \
      u32x2 pw_;                                                                   \
      pw_[0] = f2bf(WR[j][0]) | (f2bf(WR[j][1]) << 16);                            \
      pw_[1] = f2bf(WR[j][2]) | (f2bf(WR[j][3]) << 16);                            \
      *reinterpret_cast<u32x2*>(smem + (buf)*32768 + r_ * 128 + co_) = pw_;        \
    }                                                                              \
    {                                                                              \
      const int cx_ = ((l & 7) * 16) ^ ((xdr & 7) << 4);                           \
      *reinterpret_cast<u32x4*>(smem + 65536 + (buf)*8192 + xdr * 128 + cx_) = XR; \
    }                                                                              \
    __builtin_amdgcn_sched_barrier(0);                                             \
  } while (0)

#define COMPUTE(buf)                                                               \
  do {                                                                             \
    _Pragma("unroll") for (int ks = 0; ks < 2; ++ks) {                             \
      const int col_ = (ks * 64 + q * 16) ^ fxor;                                  \
      s16x8 b0_ = *reinterpret_cast<const s16x8*>(smem + (buf)*32768 + wrow0 * 128 + col_); \
      s16x8 b1_ = *reinterpret_cast<const s16x8*>(smem + (buf)*32768 + (wrow0 + 16) * 128 + col_); \
      _Pragma("unroll") for (int g = 0; g < 4; ++g) {                              \
        s16x8 a_ = *reinterpret_cast<const s16x8*>(smem + 65536 + (buf)*8192 +     \
                                                   (g * 16 + r16) * 128 + col_);   \
        acc0[g] = __builtin_amdgcn_mfma_f32_16x16x32_bf16(a_, b0_, acc0[g], 0, 0, 0); \
        acc1[g] = __builtin_amdgcn_mfma_f32_16x16x32_bf16(a_, b1_, acc1[g], 0, 0, 0); \
      }                                                                            \
    }                                                                              \
    __builtin_amdgcn_sched_barrier(0);                                             \
  } while (0)

#define SBAR()                                              \
  do {                                                      \
    asm volatile("s_waitcnt lgkmcnt(0)" ::: "memory");      \
    __builtin_amdgcn_s_barrier();                           \
    __builtin_amdgcn_sched_barrier(0);                      \
  } while (0)

  LOADW(wA, xA, 0);
  LOADW(wB, xB, 1);
  STORE(wA, xA, 0);
  SBAR();

  for (int s = 0; s < NSTEP; s += 2) {
    if (s + 2 < NSTEP) LOADW(wA, xA, s + 2);
    if (s + 1 < NSTEP) STORE(wB, xB, 1);
    COMPUTE(0);
    SBAR();
    if (s + 3 < NSTEP) LOADW(wB, xB, s + 3);
    if (s + 2 < NSTEP) STORE(wA, xA, 0);
    COMPUTE(1);
    SBAR();
  }

#undef LOADW
#undef STORE
#undef COMPUTE
#undef SBAR

  // C/D: i = i0 + wv*32 + f*16 + r16 (col=lane&15), b = g*16 + q*4 + j
#pragma unroll
  for (int g = 0; g < 4; ++g) {
    float* hp0 = ht + (size_t)(i0 + wrow0) * BATCH + g * 16 + q * 4;
    float* hp1 = ht + (size_t)(i0 + wrow0 + 16) * BATCH + g * 16 + q * 4;
#pragma unroll
    for (int j = 0; j < 4; ++j) {
      atomicAdd(hp0 + j, acc0[g][j]);
      atomicAdd(hp1 + j, acc1[g][j]);
    }
  }
}

// out_t[c][b] += ht[r][b] * w  for each nnz. One wave per nnz-chunk, lane = b.
__global__ void k_scatter(const float* __restrict__ ht, const float* __restrict__ sw,
                          const int* __restrict__ rows, const int* __restrict__ cols,
                          float* __restrict__ out_t) {
  const int w = (blockIdx.x * 256 + threadIdx.x) >> 6;  // 0..4095
  const int lane = threadIdx.x & 63;
  const int n0 = w * (NNZT / 4096);                     // 64 nnz per wave
#pragma unroll 4
  for (int n = n0; n < n0 + (NNZT / 4096); ++n) {
    const int r = rows[n];
    const int c = cols[n];
    const float wv = sw[n];
    atomicAdd(out_t + (size_t)c * BATCH + lane, ht[(size_t)r * BATCH + lane] * wv);
  }
}

// out[b][j] = leaky(out_t[j][b]) via LDS transpose. Grid 128 (j-tiles of 64).
__global__ void k_final(const float* __restrict__ out_t, float* __restrict__ out) {
  __shared__ float tile[64][65];
  const int t = threadIdx.x;
  const int j0 = blockIdx.x * 64;
  {
    const int jl = t >> 2, b0 = (t & 3) * 16;
    const float* src = out_t + (size_t)(j0 + jl) * BATCH + b0;
#pragma unroll
    for (int e = 0; e < 16; e += 4) {
      float4 v = *reinterpret_cast<const float4*>(src + e);
      tile[jl][b0 + e + 0] = v.x;
      tile[jl][b0 + e + 1] = v.y;
      tile[jl][b0 + e + 2] = v.z;
      tile[jl][b0 + e + 3] = v.w;
    }
  }
  __syncthreads();
  {
    const int bl = t >> 2, js = (t & 3) * 16;
    float* dst = out + (size_t)bl * NE + j0 + js;
#pragma unroll
    for (int e = 0; e < 16; e += 4) {
      float a0 = tile[js + e + 0][bl];
      float a1 = tile[js + e + 1][bl];
      float a2 = tile[js + e + 2][bl];
      float a3 = tile[js + e + 3][bl];
      float4 v;
      v.x = a0 >= 0.f ? a0 : 0.001f * a0;
      v.y = a1 >= 0.f ? a1 : 0.001f * a1;
      v.z = a2 >= 0.f ? a2 : 0.001f * a2;
      v.w = a3 >= 0.f ? a3 : 0.001f * a3;
      *reinterpret_cast<float4*>(dst + e) = v;
    }
  }
}

extern "C" void kernel_launch(void* const* d_in, const int* in_sizes, int n_in,
                              void* d_out, int out_size, void* d_ws, size_t ws_size,
                              hipStream_t stream) {
  const float* x = (const float*)d_in[0];
  const float* W = (const float*)d_in[1];
  const float* sw = (const float*)d_in[2];
  const int* idx = (const int*)d_in[3];  // [2][NNZ]: rows then cols
  float* out = (float*)d_out;

  char* ws = (char*)d_ws;
  float* ht = (float*)ws;                                   // 2 MB: ht[8192][64]
  float* out_t = (float*)(ws + (2 << 20));                  // 2 MB: out_t[8192][64]
  unsigned short* xbf = (unsigned short*)(ws + (4 << 20));  // 1 MB: x in bf16

  k_convert_x<<<512, 256, 0, stream>>>(x, xbf);
  k_zero<<<1024, 256, 0, stream>>>((float*)ws);  // zero ht + out_t (4 MB)
  k_dense<<<256, 512, 0, stream>>>(xbf, W, ht);
  k_scatter<<<1024, 256, 0, stream>>>(ht, sw, idx, idx + NNZT, out_t);
  k_final<<<128, 256, 0, stream>>>(out_t, out);
}